// Round 3
// baseline (27881.506 us; speedup 1.0000x reference)
//
#include <hip/hip_runtime.h>

// ============================================================================
// Seq2Seq (bi-LSTM encoder + Bahdanau-attention LSTM decoder) on gfx950.
// Inputs/outputs are FLOAT32 (per reference dtype).  Weights are converted
// once to fp16 (plenty of precision at O(0.05) magnitudes) and every GEMM
// runs as mfma_f32_16x16x32_f16 with fp32 accumulation; recurrent state (c)
// and softmax stay fp32.
// Key trick: VIN=128 -> encoder input gates x@Wih^T+b take only 128 distinct
// values per direction; precompute a 128x2048 vocab-gate table (512 KB,
// L2-resident) and GATHER per step instead of materializing 256 MB of xg.
// ============================================================================

typedef _Float16 f16;
typedef _Float16 half8 __attribute__((ext_vector_type(8)));
typedef float f32x4 __attribute__((ext_vector_type(4)));

#define MFMA16(a, b, c) __builtin_amdgcn_mfma_f32_16x16x32_f16((a), (b), (c), 0, 0, 0)

__device__ __forceinline__ float fsig(float x) {
    return __builtin_amdgcn_rcpf(1.f + __expf(-x));
}
__device__ __forceinline__ float ftanh(float x) {
    return 1.f - 2.f * __builtin_amdgcn_rcpf(1.f + __expf(2.f * x));
}

// ---------------------------------------------------------------------------
// K0: one-shot transforms: f32->fp16 weight converts, transposes of attn_W
// halves (Wh, We) and out_W, and zeroing of output t=0 row.
// ---------------------------------------------------------------------------
__global__ __launch_bounds__(256) void k_prep(
    const float* __restrict__ attn_W, const float* __restrict__ out_W,
    const float* __restrict__ enc_emb,
    const float* __restrict__ wihf, const float* __restrict__ wihb,
    const float* __restrict__ whhf, const float* __restrict__ whhb,
    const float* __restrict__ dec_emb, const float* __restrict__ dec_wih,
    const float* __restrict__ dec_whh,
    f16* __restrict__ WhT, f16* __restrict__ WeT, f16* __restrict__ outWT,
    f16* __restrict__ emb16, f16* __restrict__ wihf16, f16* __restrict__ wihb16,
    f16* __restrict__ whhf16, f16* __restrict__ whhb16, f16* __restrict__ decemb16,
    f16* __restrict__ decwih16, f16* __restrict__ decwhh16,
    float* __restrict__ out)
{
    long i = (long)blockIdx.x * 256 + threadIdx.x;
    if (i >= 3784704L) return;
    long idx = i;
    if (idx < 262144) { int e = idx >> 9, d = idx & 511; WhT[idx] = (f16)attn_W[d * 512 + e]; return; }
    idx -= 262144;
    if (idx < 262144) { int e = idx >> 9, d = idx & 511; WeT[idx] = (f16)attn_W[(512 + d) * 512 + e]; return; }
    idx -= 262144;
    if (idx < 65536)  { int v = idx >> 9, d = idx & 511; outWT[idx] = (f16)out_W[d * 128 + v]; return; }
    idx -= 65536;
    if (idx < 16384)  { int b = idx >> 7, v = idx & 127; out[b * 16384 + v] = 0.f; return; }
    idx -= 16384;
    if (idx < 16384)  { emb16[idx] = (f16)enc_emb[idx]; return; }
    idx -= 16384;
    if (idx < 131072) { wihf16[idx] = (f16)wihf[idx]; return; }
    idx -= 131072;
    if (idx < 131072) { wihb16[idx] = (f16)wihb[idx]; return; }
    idx -= 131072;
    if (idx < 262144) { whhf16[idx] = (f16)whhf[idx]; return; }
    idx -= 262144;
    if (idx < 262144) { whhb16[idx] = (f16)whhb[idx]; return; }
    idx -= 262144;
    if (idx < 16384)  { decemb16[idx] = (f16)dec_emb[idx]; return; }
    idx -= 16384;
    if (idx < 1310720){ decwih16[idx] = (f16)dec_wih[idx]; return; }
    idx -= 1310720;
    if (idx < 1048576){ decwhh16[idx] = (f16)dec_whh[idx]; return; }
}

// ---------------------------------------------------------------------------
// K_vocab: xg_vocab[v][n] = emb[v] @ [Wih_f|Wih_b]^T + [b_f|b_b], v<128,
// n<2048 (fwd 1024 | bwd 1024).  16 blocks (n-tiles of 128); 4 waves 2x2.
// ---------------------------------------------------------------------------
__global__ __launch_bounds__(256) void k_vocab(
    const f16* __restrict__ emb, const f16* __restrict__ wihf,
    const f16* __restrict__ wihb, const float* __restrict__ bf_,
    const float* __restrict__ bb_, f16* __restrict__ xg_vocab)
{
    int bn = blockIdx.x;
    int tid = threadIdx.x, wave = tid >> 6, lane = tid & 63;
    int col = lane & 15, quad = lane >> 4;
    int wr = wave >> 1, wc = wave & 1;

    f32x4 acc[4][4] = {};
    for (int ks = 0; ks < 4; ++ks) {
        int k0 = ks * 32 + quad * 8;
        half8 a[4], bfr[4];
        for (int i = 0; i < 4; ++i)
            a[i] = *(const half8*)(emb + (wr * 64 + i * 16 + col) * 128 + k0);
        for (int j = 0; j < 4; ++j) {
            int n = bn * 128 + wc * 64 + j * 16 + col;
            const f16* wp = (n < 1024) ? (wihf + n * 128) : (wihb + (n - 1024) * 128);
            bfr[j] = *(const half8*)(wp + k0);
        }
        for (int i = 0; i < 4; ++i)
            for (int j = 0; j < 4; ++j)
                acc[i][j] = MFMA16(a[i], bfr[j], acc[i][j]);
    }
    for (int j = 0; j < 4; ++j) {
        int n = bn * 128 + wc * 64 + j * 16 + col;
        float bias = (n < 1024) ? bf_[n] : bb_[n - 1024];
        for (int i = 0; i < 4; ++i) {
            int vbase = wr * 64 + i * 16 + quad * 4;
            for (int r = 0; r < 4; ++r)
                xg_vocab[(vbase + r) * 2048 + n] = (f16)(acc[i][j][r] + bias);
        }
    }
}

// ---------------------------------------------------------------------------
// K_enc: encoder recurrent scan, both directions. 16 persistent blocks
// (2 dirs x 8 batch-groups of 16), zero grid syncs. Wave w owns h-cols
// [w*64, w*64+64) for ALL FOUR gate groups -> i/f/g/o land in the same lane
// so the LSTM update is fully in-lane; c lives in VGPRs.  Input gates come
// from the L2-resident vocab table gathered by token.  Whh streamed from L2
// every step (~512KB/CU/step, the expected bottleneck).
// ---------------------------------------------------------------------------
__global__ __launch_bounds__(256) void k_enc(
    const int* __restrict__ src, const f16* __restrict__ xg_vocab,
    const f16* __restrict__ whhf, const f16* __restrict__ whhb,
    f16* __restrict__ enc_out, f16* __restrict__ hdec0, float* __restrict__ c_ws)
{
    int blk = blockIdx.x;
    int dir = blk >> 3, bbase = (blk & 7) * 16;
    int tid = threadIdx.x, wave = tid >> 6, lane = tid & 63;
    int col = lane & 15, quad = lane >> 4;
    const f16* whh = dir ? whhb : whhf;

    __shared__ f16 hb[16][264];   // h (fp16) for next step's A-frags; +8 pad
    __shared__ int stok[16];      // this step's tokens for the 16 batch rows
    {
        int tb = tid >> 4, tc = (tid & 15) * 16;
        for (int i = 0; i < 16; ++i) hb[tb][tc + i] = (f16)0.f;
    }
    float cc[4][4] = {};          // c state: [nt][r] for (hcol, batch) owned by lane
    __syncthreads();

    for (int t = 0; t < 512; ++t) {
        int ts = dir ? (511 - t) : t;
        if (tid < 16) stok[tid] = src[(bbase + tid) * 512 + ts];
        // preload A-frags (h) from LDS
        half8 a[8];
        for (int kk = 0; kk < 8; ++kk)
            a[kk] = *(const half8*)(&hb[col][kk * 32 + quad * 8]);
        __syncthreads();   // preload reads + stok writes done

        f32x4 acc[4][4] = {};   // [gate-group][nt]
        for (int kk = 0; kk < 8; ++kk) {
            for (int g = 0; g < 4; ++g)
                for (int nt = 0; nt < 4; ++nt) {
                    int n = g * 256 + wave * 64 + nt * 16 + col;
                    half8 bfr = *(const half8*)(whh + n * 256 + kk * 32 + quad * 8);
                    acc[g][nt] = MFMA16(a[kk], bfr, acc[g][nt]);
                }
        }
        // in-lane LSTM update
        for (int nt = 0; nt < 4; ++nt) {
            int hcol = wave * 64 + nt * 16 + col;
            for (int r = 0; r < 4; ++r) {
                int b = quad * 4 + r;
                const f16* xv = xg_vocab + stok[b] * 2048 + dir * 1024;
                float gi = (float)xv[0 * 256 + hcol] + acc[0][nt][r];
                float gf = (float)xv[1 * 256 + hcol] + acc[1][nt][r];
                float gg = (float)xv[2 * 256 + hcol] + acc[2][nt][r];
                float go = (float)xv[3 * 256 + hcol] + acc[3][nt][r];
                float ig = fsig(gi), fg = fsig(gf), g2 = ftanh(gg), og = fsig(go);
                float cv = fg * cc[nt][r] + ig * g2;
                cc[nt][r] = cv;
                float h = og * ftanh(cv);
                f16 h16 = (f16)h;
                hb[b][hcol] = h16;
                enc_out[((bbase + b) * 512 + ts) * 512 + dir * 256 + hcol] = h16;
            }
        }
        __syncthreads();   // hb complete for next step's preload
    }
    // final states -> decoder init
    for (int nt = 0; nt < 4; ++nt) {
        int hcol = wave * 64 + nt * 16 + col;
        for (int r = 0; r < 4; ++r) {
            int b = quad * 4 + r;
            hdec0[(bbase + b) * 512 + dir * 256 + hcol] = hb[b][hcol];
            c_ws[(bbase + b) * 512 + dir * 256 + hcol] = cc[nt][r];
        }
    }
}

// ---------------------------------------------------------------------------
// K_proj: enc_proj = enc_out @ We.  M=65536, N=512, K=512.  2048 blocks.
// ---------------------------------------------------------------------------
__global__ __launch_bounds__(256) void k_proj(
    const f16* __restrict__ enc_out, const f16* __restrict__ WeT,
    f16* __restrict__ proj)
{
    int blk = blockIdx.x;
    int bm = blk & 511, bn = blk >> 9;
    int tid = threadIdx.x, wave = tid >> 6, lane = tid & 63;
    int col = lane & 15, quad = lane >> 4;
    int wr = wave >> 1, wc = wave & 1;

    f32x4 acc[4][4] = {};
    for (int ks = 0; ks < 16; ++ks) {
        int k0 = ks * 32 + quad * 8;
        half8 a[4], bfr[4];
        for (int i = 0; i < 4; ++i) {
            int m = bm * 128 + wr * 64 + i * 16 + col;
            a[i] = *(const half8*)(enc_out + m * 512 + k0);
        }
        for (int j = 0; j < 4; ++j) {
            int n = bn * 128 + wc * 64 + j * 16 + col;
            bfr[j] = *(const half8*)(WeT + n * 512 + k0);
        }
        for (int i = 0; i < 4; ++i)
            for (int j = 0; j < 4; ++j)
                acc[i][j] = MFMA16(a[i], bfr[j], acc[i][j]);
    }
    for (int j = 0; j < 4; ++j) {
        int n = bn * 128 + wc * 64 + j * 16 + col;
        for (int i = 0; i < 4; ++i) {
            int mbase = bm * 128 + wr * 64 + i * 16 + quad * 4;
            for (int r = 0; r < 4; ++r)
                proj[(mbase + r) * 512 + n] = (f16)acc[i][j][r];
        }
    }
}

// ---------------------------------------------------------------------------
// K_qinit: initial q-partials from encoder-final h.  16 blocks (one per
// K-slice of 32).  qpart[j][b][e] = sum_{k in slice j} h0[b][k] * WhT[e][k].
// ---------------------------------------------------------------------------
__global__ __launch_bounds__(256) void k_qinit(
    const f16* __restrict__ h0, const f16* __restrict__ WhT,
    float* __restrict__ qpart)
{
    int j = blockIdx.x;
    int tid = threadIdx.x, wave = tid >> 6, lane = tid & 63;
    int col = lane & 15, quad = lane >> 4;
    half8 a[2];
    for (int i = 0; i < 2; ++i)
        a[i] = *(const half8*)(h0 + (wave * 32 + i * 16 + col) * 512 + j * 32 + quad * 8);
    for (int nt = 0; nt < 32; ++nt) {
        half8 bfr = *(const half8*)(WhT + (nt * 16 + col) * 512 + j * 32 + quad * 8);
        f32x4 q0 = {}, q1 = {};
        q0 = MFMA16(a[0], bfr, q0);
        q1 = MFMA16(a[1], bfr, q1);
        for (int r = 0; r < 4; ++r) {
            qpart[(j * 128 + wave * 32 + quad * 4 + r) * 512 + nt * 16 + col] = q0[r];
            qpart[(j * 128 + wave * 32 + 16 + quad * 4 + r) * 512 + nt * 16 + col] = q1[r];
        }
    }
}

// ---------------------------------------------------------------------------
// K_att (per decoder step): one block per batch row.
// q = sum(qpart) + attn_b; scores_s = v . tanh(q + proj[b,s]); softmax;
// ctx = sum aw_s * enc_out[b,s]; x = [dec_emb[tok] | ctx].
// ---------------------------------------------------------------------------
__global__ __launch_bounds__(256) void k_att(
    const f16* __restrict__ proj, const f16* __restrict__ enc_out,
    const float* __restrict__ qpart, const float* __restrict__ attn_b,
    const float* __restrict__ attn_v, const int* __restrict__ trg,
    const f16* __restrict__ dec_emb, f16* __restrict__ xrow, int t)
{
    int b = blockIdx.x;
    int tid = threadIdx.x, wave = tid >> 6, lane = tid & 63;
    __shared__ float q[512];
    __shared__ float sc[512];
    __shared__ float wred[4], wred2[4];

    for (int e = tid; e < 512; e += 256) {
        float s = attn_b[e];
        for (int jj = 0; jj < 16; ++jj) s += qpart[(jj * 128 + b) * 512 + e];
        q[e] = s;
    }
    __syncthreads();

    float qreg[8], vreg[8];
    for (int u = 0; u < 8; ++u) {
        int e = lane * 8 + u;
        qreg[u] = q[e];
        vreg[u] = attn_v[e];
    }
    // scores: each wave handles s = it*4 + wave; lanes split e (8 each)
    for (int it = 0; it < 128; ++it) {
        int s = it * 4 + wave;
        half8 p = *(const half8*)(proj + (b * 512 + s) * 512 + lane * 8);
        float part = 0.f;
        for (int u = 0; u < 8; ++u)
            part += vreg[u] * ftanh(qreg[u] + (float)p[u]);
        for (int o = 32; o; o >>= 1) part += __shfl_xor(part, o);
        if (lane == 0) sc[s] = part;
    }
    __syncthreads();

    // softmax over 512
    float s0 = sc[tid], s1 = sc[tid + 256];
    float mv = fmaxf(s0, s1);
    for (int o = 32; o; o >>= 1) mv = fmaxf(mv, __shfl_xor(mv, o));
    if (lane == 0) wred[wave] = mv;
    __syncthreads();
    float M = fmaxf(fmaxf(wred[0], wred[1]), fmaxf(wred[2], wred[3]));
    float e0 = __expf(s0 - M), e1 = __expf(s1 - M);
    float sm = e0 + e1;
    for (int o = 32; o; o >>= 1) sm += __shfl_xor(sm, o);
    if (lane == 0) wred2[wave] = sm;
    __syncthreads();
    float inv = 1.f / (wred2[0] + wred2[1] + wred2[2] + wred2[3]);
    sc[tid] = e0 * inv;
    sc[tid + 256] = e1 * inv;
    __syncthreads();

    // ctx: thread owns 2 d's; 4 independent s-streams to break the acc chain
    int d0 = tid * 2;
    float acc0[4] = {}, acc1[4] = {};
    for (int s4 = 0; s4 < 128; ++s4) {
        for (int j3 = 0; j3 < 4; ++j3) {
            int s = j3 * 128 + s4;
            float w = sc[s];
            const f16* er = enc_out + (b * 512 + s) * 512 + d0;
            acc0[j3] += w * (float)er[0];
            acc1[j3] += w * (float)er[1];
        }
    }
    float c0 = acc0[0] + acc0[1] + acc0[2] + acc0[3];
    float c1 = acc1[0] + acc1[1] + acc1[2] + acc1[3];

    int tok = trg[b * 128 + t];
    if (tid < 64) {
        xrow[b * 640 + tid * 2]     = dec_emb[tok * 128 + tid * 2];
        xrow[b * 640 + tid * 2 + 1] = dec_emb[tok * 128 + tid * 2 + 1];
    }
    xrow[b * 640 + 128 + d0]     = (f16)c0;
    xrow[b * 640 + 128 + d0 + 1] = (f16)c1;
}

// ---------------------------------------------------------------------------
// K_gates (per decoder step): 16 blocks; block j owns matched n-slices
// {g*512 + j*32 .. +32} for g=0..3 so i/f/g/o land in the same lane.
// gates = [x|h] @ [dec_Wih|dec_Whh]^T + b; in-lane LSTM update (c fp32 in ws);
// then fused q-partial GEMM for next step's attention.  Zero barriers.
// ---------------------------------------------------------------------------
__global__ __launch_bounds__(256) void k_gates(
    const f16* __restrict__ x, const f16* __restrict__ hprev,
    const f16* __restrict__ wih, const f16* __restrict__ whh,
    const float* __restrict__ dec_b, float* __restrict__ c_ws,
    f16* __restrict__ hnext, f16* __restrict__ hhist,
    const f16* __restrict__ WhT, float* __restrict__ qpart, int t)
{
    int j = blockIdx.x;
    int tid = threadIdx.x, wave = tid >> 6, lane = tid & 63;
    int col = lane & 15, quad = lane >> 4;
    __shared__ f16 hsl[128][40];   // this block's new h-slice (32 cols + pad)

    f32x4 acc[2][8] = {};   // [m-tile][jt], jt = g*2+u
    for (int ks = 0; ks < 36; ++ks) {
        int k0 = ks * 32 + quad * 8;
        half8 a[2];
        if (ks < 20) {
            for (int i = 0; i < 2; ++i)
                a[i] = *(const half8*)(x + (wave * 32 + i * 16 + col) * 640 + k0);
        } else {
            for (int i = 0; i < 2; ++i)
                a[i] = *(const half8*)(hprev + (wave * 32 + i * 16 + col) * 512 + (k0 - 640));
        }
        for (int jt = 0; jt < 8; ++jt) {
            int g = jt >> 1, u = jt & 1;
            int n = g * 512 + j * 32 + u * 16 + col;
            half8 bfr;
            if (ks < 20) bfr = *(const half8*)(wih + n * 640 + k0);
            else         bfr = *(const half8*)(whh + n * 512 + (k0 - 640));
            acc[0][jt] = MFMA16(a[0], bfr, acc[0][jt]);
            acc[1][jt] = MFMA16(a[1], bfr, acc[1][jt]);
        }
    }
    float bias[8];
    for (int jt = 0; jt < 8; ++jt) {
        int g = jt >> 1, u = jt & 1;
        bias[jt] = dec_b[g * 512 + j * 32 + u * 16 + col];
    }
    for (int i = 0; i < 2; ++i) {
        for (int r = 0; r < 4; ++r) {
            int b = wave * 32 + i * 16 + quad * 4 + r;
            for (int u = 0; u < 2; ++u) {
                int hl = u * 16 + col, hcol = j * 32 + hl;
                float gi = acc[i][0 + u][r] + bias[0 + u];
                float gf = acc[i][2 + u][r] + bias[2 + u];
                float gg = acc[i][4 + u][r] + bias[4 + u];
                float go = acc[i][6 + u][r] + bias[6 + u];
                float ig = fsig(gi), fg = fsig(gf), g2 = ftanh(gg), og = fsig(go);
                float cv = fg * c_ws[b * 512 + hcol] + ig * g2;
                c_ws[b * 512 + hcol] = cv;
                float h = og * ftanh(cv);
                f16 h16 = (f16)h;
                hnext[b * 512 + hcol] = h16;
                hhist[(t * 128 + b) * 512 + hcol] = h16;
                hsl[b][hl] = h16;   // same-wave rows only -> no barrier needed
            }
        }
    }
    // fused q-partials for next step (wave reads only its own hsl rows)
    half8 aq[2];
    for (int i = 0; i < 2; ++i)
        aq[i] = *(const half8*)(&hsl[wave * 32 + i * 16 + col][quad * 8]);
    for (int nt = 0; nt < 32; ++nt) {
        half8 bq = *(const half8*)(WhT + (nt * 16 + col) * 512 + j * 32 + quad * 8);
        f32x4 q0 = {}, q1 = {};
        q0 = MFMA16(aq[0], bq, q0);
        q1 = MFMA16(aq[1], bq, q1);
        for (int r = 0; r < 4; ++r) {
            qpart[(j * 128 + wave * 32 + quad * 4 + r) * 512 + nt * 16 + col] = q0[r];
            qpart[(j * 128 + wave * 32 + 16 + quad * 4 + r) * 512 + nt * 16 + col] = q1[r];
        }
    }
}

// ---------------------------------------------------------------------------
// K_logits: batched over all 127 steps.  out[b][t+1][:] = h_t[b] @ out_W + b.
// ---------------------------------------------------------------------------
__global__ __launch_bounds__(256) void k_logits(
    const f16* __restrict__ hhist, const f16* __restrict__ outWT,
    const float* __restrict__ out_b, float* __restrict__ out)
{
    int bt = blockIdx.x;   // 0..126
    int tid = threadIdx.x, wave = tid >> 6, lane = tid & 63;
    int col = lane & 15, quad = lane >> 4;
    f32x4 acc[2][8] = {};
    for (int ks = 0; ks < 16; ++ks) {
        int k0 = ks * 32 + quad * 8;
        half8 a[2];
        for (int i = 0; i < 2; ++i)
            a[i] = *(const half8*)(hhist + (bt * 128 + wave * 32 + i * 16 + col) * 512 + k0);
        for (int jt = 0; jt < 8; ++jt) {
            half8 bfr = *(const half8*)(outWT + (jt * 16 + col) * 512 + k0);
            acc[0][jt] = MFMA16(a[0], bfr, acc[0][jt]);
            acc[1][jt] = MFMA16(a[1], bfr, acc[1][jt]);
        }
    }
    for (int jt = 0; jt < 8; ++jt) {
        float bias = out_b[jt * 16 + col];
        for (int i = 0; i < 2; ++i)
            for (int r = 0; r < 4; ++r) {
                int br = wave * 32 + i * 16 + quad * 4 + r;
                out[br * 16384 + (bt + 1) * 128 + jt * 16 + col] = acc[i][jt][r] + bias;
            }
    }
}

// ---------------------------------------------------------------------------
extern "C" void kernel_launch(void* const* d_in, const int* in_sizes, int n_in,
                              void* d_out, int out_size, void* d_ws, size_t ws_size,
                              hipStream_t stream)
{
    (void)in_sizes; (void)n_in; (void)out_size;
    // Guard: workspace carve total ~156.2 MiB; bail cleanly if too small.
    if (ws_size < 164000000) return;

    const int*   src     = (const int*)d_in[0];
    const int*   trg     = (const int*)d_in[1];
    const float* enc_emb = (const float*)d_in[2];
    const float* wihf    = (const float*)d_in[3];
    const float* whhf    = (const float*)d_in[4];
    const float* bf_     = (const float*)d_in[5];
    const float* wihb    = (const float*)d_in[6];
    const float* whhb    = (const float*)d_in[7];
    const float* bb_     = (const float*)d_in[8];
    const float* dec_emb = (const float*)d_in[9];
    const float* dec_wih = (const float*)d_in[10];
    const float* dec_whh = (const float*)d_in[11];
    const float* dec_b   = (const float*)d_in[12];
    const float* attn_W  = (const float*)d_in[13];
    const float* attn_b  = (const float*)d_in[14];
    const float* attn_v  = (const float*)d_in[15];
    const float* out_W   = (const float*)d_in[16];
    const float* out_b   = (const float*)d_in[17];
    float* out = (float*)d_out;

    char* p = (char*)d_ws;
    auto carve = [&](size_t n) { char* r = p; p += ((n + 255) & ~(size_t)255); return r; };
    f16*   enc_out  = (f16*)  carve(67108864);   // 65536 x 512 fp16
    f16*   proj     = (f16*)  carve(67108864);   // 65536 x 512 fp16
    f16*   WhT      = (f16*)  carve(524288);
    f16*   WeT      = (f16*)  carve(524288);
    f16*   outWT    = (f16*)  carve(131072);
    f16*   emb16    = (f16*)  carve(32768);
    f16*   wihf16   = (f16*)  carve(262144);
    f16*   wihb16   = (f16*)  carve(262144);
    f16*   whhf16   = (f16*)  carve(524288);
    f16*   whhb16   = (f16*)  carve(524288);
    f16*   decemb16 = (f16*)  carve(32768);
    f16*   decwih16 = (f16*)  carve(2621440);
    f16*   decwhh16 = (f16*)  carve(2097152);
    float* qpart    = (float*)carve(4194304);    // 16 x 128 x 512 fp32
    f16*   hdec0    = (f16*)  carve(131072);
    f16*   hdec1    = (f16*)  carve(131072);
    float* c_ws     = (float*)carve(262144);
    f16*   x16      = (f16*)  carve(163840);     // 128 x 640
    f16*   hhist    = (f16*)  carve(16646144);   // 127 x 128 x 512
    f16*   xg_vocab = (f16*)  carve(524288);     // 128 x 2048 fp16

    k_prep<<<14784, 256, 0, stream>>>(attn_W, out_W, enc_emb, wihf, wihb, whhf, whhb,
                                      dec_emb, dec_wih, dec_whh,
                                      WhT, WeT, outWT, emb16, wihf16, wihb16,
                                      whhf16, whhb16, decemb16, decwih16, decwhh16, out);
    k_vocab<<<16, 256, 0, stream>>>(emb16, wihf16, wihb16, bf_, bb_, xg_vocab);
    k_enc<<<16, 256, 0, stream>>>(src, xg_vocab, whhf16, whhb16, enc_out, hdec0, c_ws);
    k_proj<<<2048, 256, 0, stream>>>(enc_out, WeT, proj);
    k_qinit<<<16, 256, 0, stream>>>(hdec0, WhT, qpart);
    for (int t = 0; t < 127; ++t) {
        k_att<<<128, 256, 0, stream>>>(proj, enc_out, qpart, attn_b, attn_v,
                                       trg, decemb16, x16, t);
        f16* hin  = (t & 1) ? hdec1 : hdec0;
        f16* hout = (t & 1) ? hdec0 : hdec1;
        k_gates<<<16, 256, 0, stream>>>(x16, hin, decwih16, decwhh16, dec_b,
                                        c_ws, hout, hhist, WhT, qpart, t);
    }
    k_logits<<<127, 256, 0, stream>>>(hhist, outWT, out_b, out);
}

// Round 4
// 15259.256 us; speedup vs baseline: 1.8272x; 1.8272x over previous
//
#include <hip/hip_runtime.h>

// ============================================================================
// Seq2Seq (bi-LSTM encoder + Bahdanau-attention LSTM decoder) on gfx950.
// fp32 in/out; fp16 internal with fp32 accum/state.
// R4: all MFMA operands in "fragment order" (packed so each wave load is a
// single coalesced 1KB transaction); k_enc/k_att widened to 512 threads;
// k_enc input gates staged via LDS; load batching everywhere.
// ============================================================================

typedef _Float16 f16;
typedef _Float16 half8 __attribute__((ext_vector_type(8)));
typedef float f32x4 __attribute__((ext_vector_type(4)));

#define MFMA16(a, b, c) __builtin_amdgcn_mfma_f32_16x16x32_f16((a), (b), (c), 0, 0, 0)

__device__ __forceinline__ float fsig(float x) {
    return __builtin_amdgcn_rcpf(1.f + __expf(-x));
}
__device__ __forceinline__ float ftanh(float x) {
    return 1.f - 2.f * __builtin_amdgcn_rcpf(1.f + __expf(2.f * x));
}
// fragment-order index for an MFMA operand matrix with K columns (KS=K/32
// k-slices): element (row m or n, col k) of a 16-row tile.
__device__ __forceinline__ int frag_idx(int m, int k, int KS) {
    return (((m >> 4) * KS + (k >> 5)) * 64 + (((k >> 3) & 3) * 16 + (m & 15))) * 8 + (k & 7);
}

// ---------------------------------------------------------------------------
// K0: one-shot: pack weights to fragment order (f32 -> f16), plain converts,
// zero out t=0 output row.
// ---------------------------------------------------------------------------
__global__ __launch_bounds__(256) void k_prep(
    const float* __restrict__ attn_W, const float* __restrict__ out_W,
    const float* __restrict__ enc_emb,
    const float* __restrict__ wihf, const float* __restrict__ wihb,
    const float* __restrict__ whhf, const float* __restrict__ whhb,
    const float* __restrict__ dec_emb, const float* __restrict__ dec_wih,
    const float* __restrict__ dec_whh,
    f16* __restrict__ WhT_sw, f16* __restrict__ outWT_sw,
    f16* __restrict__ whhf_sw, f16* __restrict__ whhb_sw,
    f16* __restrict__ decwih_sw, f16* __restrict__ decwhh_sw,
    f16* __restrict__ WeT, f16* __restrict__ emb16,
    f16* __restrict__ wihf16, f16* __restrict__ wihb16,
    f16* __restrict__ decemb16, float* __restrict__ out)
{
    long i = (long)blockIdx.x * 256 + threadIdx.x;
    if (i >= 3784704L) return;
    long idx = i;
    // helpers decoded per segment: j = idx&7, lane=(idx>>3)&63, c=lane&15, q=lane>>4
    if (idx < 262144) {  // WhT_sw: N=512(e) x K=512(d), 16 ks
        int j = idx & 7, lane = (idx >> 3) & 63, c = lane & 15, q = lane >> 4;
        int ks = (idx >> 9) & 15, nt = idx >> 13;
        WhT_sw[idx] = (f16)attn_W[(ks * 32 + q * 8 + j) * 512 + nt * 16 + c];
        return;
    }
    idx -= 262144;
    if (idx < 65536) {   // outWT_sw: N=128(v) x K=512(d), 16 ks
        int j = idx & 7, lane = (idx >> 3) & 63, c = lane & 15, q = lane >> 4;
        int ks = (idx >> 9) & 15, nt = idx >> 13;
        outWT_sw[idx] = (f16)out_W[(ks * 32 + q * 8 + j) * 128 + nt * 16 + c];
        return;
    }
    idx -= 65536;
    if (idx < 262144) {  // whhf_sw: N=1024 x K=256, 8 ks
        int j = idx & 7, lane = (idx >> 3) & 63, c = lane & 15, q = lane >> 4;
        int ks = (idx >> 9) & 7, nt = idx >> 12;
        whhf_sw[idx] = (f16)whhf[(nt * 16 + c) * 256 + ks * 32 + q * 8 + j];
        return;
    }
    idx -= 262144;
    if (idx < 262144) {  // whhb_sw
        int j = idx & 7, lane = (idx >> 3) & 63, c = lane & 15, q = lane >> 4;
        int ks = (idx >> 9) & 7, nt = idx >> 12;
        whhb_sw[idx] = (f16)whhb[(nt * 16 + c) * 256 + ks * 32 + q * 8 + j];
        return;
    }
    idx -= 262144;
    if (idx < 1310720) { // decwih_sw: N=2048 x K=640, 20 ks
        int j = idx & 7, lane = (idx >> 3) & 63, c = lane & 15, q = lane >> 4;
        int r2 = idx >> 9; int ks = r2 % 20, nt = r2 / 20;
        decwih_sw[idx] = (f16)dec_wih[(nt * 16 + c) * 640 + ks * 32 + q * 8 + j];
        return;
    }
    idx -= 1310720;
    if (idx < 1048576) { // decwhh_sw: N=2048 x K=512, 16 ks
        int j = idx & 7, lane = (idx >> 3) & 63, c = lane & 15, q = lane >> 4;
        int ks = (idx >> 9) & 15, nt = idx >> 13;
        decwhh_sw[idx] = (f16)dec_whh[(nt * 16 + c) * 512 + ks * 32 + q * 8 + j];
        return;
    }
    idx -= 1048576;
    if (idx < 262144) { int e = idx >> 9, d = idx & 511; WeT[idx] = (f16)attn_W[(512 + d) * 512 + e]; return; }
    idx -= 262144;
    if (idx < 16384)  { emb16[idx] = (f16)enc_emb[idx]; return; }
    idx -= 16384;
    if (idx < 131072) { wihf16[idx] = (f16)wihf[idx]; return; }
    idx -= 131072;
    if (idx < 131072) { wihb16[idx] = (f16)wihb[idx]; return; }
    idx -= 131072;
    if (idx < 16384)  { decemb16[idx] = (f16)dec_emb[idx]; return; }
    idx -= 16384;
    if (idx < 16384)  { int b = idx >> 7, v = idx & 127; out[b * 16384 + v] = 0.f; return; }
}

// ---------------------------------------------------------------------------
// K_vocab: xg_vocab[v][n] = emb[v] @ [Wih_f|Wih_b]^T + [b_f|b_b] (once).
// ---------------------------------------------------------------------------
__global__ __launch_bounds__(256) void k_vocab(
    const f16* __restrict__ emb, const f16* __restrict__ wihf,
    const f16* __restrict__ wihb, const float* __restrict__ bf_,
    const float* __restrict__ bb_, f16* __restrict__ xg_vocab)
{
    int bn = blockIdx.x;
    int tid = threadIdx.x, wave = tid >> 6, lane = tid & 63;
    int col = lane & 15, quad = lane >> 4;
    int wr = wave >> 1, wc = wave & 1;

    f32x4 acc[4][4] = {};
    for (int ks = 0; ks < 4; ++ks) {
        int k0 = ks * 32 + quad * 8;
        half8 a[4], bfr[4];
        for (int i = 0; i < 4; ++i)
            a[i] = *(const half8*)(emb + (wr * 64 + i * 16 + col) * 128 + k0);
        for (int j = 0; j < 4; ++j) {
            int n = bn * 128 + wc * 64 + j * 16 + col;
            const f16* wp = (n < 1024) ? (wihf + n * 128) : (wihb + (n - 1024) * 128);
            bfr[j] = *(const half8*)(wp + k0);
        }
        for (int i = 0; i < 4; ++i)
            for (int j = 0; j < 4; ++j)
                acc[i][j] = MFMA16(a[i], bfr[j], acc[i][j]);
    }
    for (int j = 0; j < 4; ++j) {
        int n = bn * 128 + wc * 64 + j * 16 + col;
        float bias = (n < 1024) ? bf_[n] : bb_[n - 1024];
        for (int i = 0; i < 4; ++i) {
            int vbase = wr * 64 + i * 16 + quad * 4;
            for (int r = 0; r < 4; ++r)
                xg_vocab[(vbase + r) * 2048 + n] = (f16)(acc[i][j][r] + bias);
        }
    }
}

// ---------------------------------------------------------------------------
// K_enc: encoder scan, 16 persistent blocks (2 dir x 8 batch-groups of 16),
// 512 threads (8 waves; wave owns 32 h-cols for all 4 gate groups).
// Whh in fragment order -> every B-load is one coalesced 1KB transaction.
// Input gates staged to LDS via coalesced half8 loads each step.
// ---------------------------------------------------------------------------
__global__ __launch_bounds__(512) void k_enc(
    const int* __restrict__ src, const f16* __restrict__ xg_vocab,
    const f16* __restrict__ whhf_sw, const f16* __restrict__ whhb_sw,
    f16* __restrict__ enc_out, f16* __restrict__ hdec0, float* __restrict__ c_ws)
{
    int blk = blockIdx.x;
    int dir = blk >> 3, bbase = (blk & 7) * 16;
    int tid = threadIdx.x, wave = tid >> 6, lane = tid & 63;
    int col = lane & 15, quad = lane >> 4;
    const f16* whh = dir ? whhb_sw : whhf_sw;

    __shared__ f16 hb[16][264];     // h for next step's A-frags (+pad)
    __shared__ f16 xvb[16][1032];   // this step's input-gate rows (+pad)
    __shared__ int stok[16];
    for (int z = tid; z < 16 * 264; z += 512) ((f16*)hb)[z] = (f16)0.f;
    float cc[2][4] = {};            // c state [nt][r]
    __syncthreads();

    for (int t = 0; t < 512; ++t) {
        int ts = dir ? (511 - t) : t;
        if (tid < 16) stok[tid] = src[(bbase + tid) * 512 + ts];
        // preload A-frags (h) from LDS
        half8 a[8];
        #pragma unroll
        for (int kk = 0; kk < 8; ++kk)
            a[kk] = *(const half8*)(&hb[col][kk * 32 + quad * 8]);
        __syncthreads();   // a-reads + stok writes done

        // stage input-gate rows -> LDS (coalesced), overlapped with MFMAs
        #pragma unroll
        for (int it = 0; it < 4; ++it) {
            int cnk = it * 512 + tid;
            int row = cnk >> 7, off = (cnk & 127) * 8;
            *(half8*)(&xvb[row][off]) =
                *(const half8*)(xg_vocab + stok[row] * 2048 + dir * 1024 + off);
        }

        f32x4 acc[4][2] = {};   // [gate][nt]
        #pragma unroll
        for (int kk = 0; kk < 8; ++kk) {
            half8 bv[8];
            #pragma unroll
            for (int g = 0; g < 4; ++g)
                #pragma unroll
                for (int nt = 0; nt < 2; ++nt) {
                    int tile = g * 16 + wave * 2 + nt;
                    bv[g * 2 + nt] = *(const half8*)(whh + ((tile * 8 + kk) * 64 + lane) * 8);
                }
            #pragma unroll
            for (int g = 0; g < 4; ++g)
                #pragma unroll
                for (int nt = 0; nt < 2; ++nt)
                    acc[g][nt] = MFMA16(a[kk], bv[g * 2 + nt], acc[g][nt]);
        }
        __syncthreads();   // xvb complete

        // in-lane LSTM update
        #pragma unroll
        for (int nt = 0; nt < 2; ++nt) {
            int hcol = wave * 32 + nt * 16 + col;
            #pragma unroll
            for (int r = 0; r < 4; ++r) {
                int b = quad * 4 + r;
                float gi = (float)xvb[b][0 * 256 + hcol] + acc[0][nt][r];
                float gf = (float)xvb[b][1 * 256 + hcol] + acc[1][nt][r];
                float gg = (float)xvb[b][2 * 256 + hcol] + acc[2][nt][r];
                float go = (float)xvb[b][3 * 256 + hcol] + acc[3][nt][r];
                float ig = fsig(gi), fg = fsig(gf), g2 = ftanh(gg), og = fsig(go);
                float cv = fg * cc[nt][r] + ig * g2;
                cc[nt][r] = cv;
                float h = og * ftanh(cv);
                f16 h16 = (f16)h;
                hb[b][hcol] = h16;
                enc_out[((size_t)(bbase + b) * 512 + ts) * 512 + dir * 256 + hcol] = h16;
            }
        }
        __syncthreads();   // hb complete
    }
    // final states: h -> fragment-order hdec0 (K=512), c -> plain c_ws
    #pragma unroll
    for (int nt = 0; nt < 2; ++nt) {
        int hcol = wave * 32 + nt * 16 + col;
        #pragma unroll
        for (int r = 0; r < 4; ++r) {
            int b = quad * 4 + r;
            int m = bbase + b, k = dir * 256 + hcol;
            hdec0[frag_idx(m, k, 16)] = hb[b][hcol];
            c_ws[m * 512 + k] = cc[nt][r];
        }
    }
}

// ---------------------------------------------------------------------------
// K_proj: enc_proj = enc_out @ We (once).  M=65536, N=512, K=512.
// ---------------------------------------------------------------------------
__global__ __launch_bounds__(256) void k_proj(
    const f16* __restrict__ enc_out, const f16* __restrict__ WeT,
    f16* __restrict__ proj)
{
    int blk = blockIdx.x;
    int bm = blk & 511, bn = blk >> 9;
    int tid = threadIdx.x, wave = tid >> 6, lane = tid & 63;
    int col = lane & 15, quad = lane >> 4;
    int wr = wave >> 1, wc = wave & 1;

    f32x4 acc[4][4] = {};
    for (int ks = 0; ks < 16; ++ks) {
        int k0 = ks * 32 + quad * 8;
        half8 a[4], bfr[4];
        for (int i = 0; i < 4; ++i) {
            int m = bm * 128 + wr * 64 + i * 16 + col;
            a[i] = *(const half8*)(enc_out + (size_t)m * 512 + k0);
        }
        for (int j = 0; j < 4; ++j) {
            int n = bn * 128 + wc * 64 + j * 16 + col;
            bfr[j] = *(const half8*)(WeT + n * 512 + k0);
        }
        for (int i = 0; i < 4; ++i)
            for (int j = 0; j < 4; ++j)
                acc[i][j] = MFMA16(a[i], bfr[j], acc[i][j]);
    }
    for (int j = 0; j < 4; ++j) {
        int n = bn * 128 + wc * 64 + j * 16 + col;
        for (int i = 0; i < 4; ++i) {
            int mbase = bm * 128 + wr * 64 + i * 16 + quad * 4;
            for (int r = 0; r < 4; ++r)
                proj[(size_t)(mbase + r) * 512 + n] = (f16)acc[i][j][r];
        }
    }
}

// ---------------------------------------------------------------------------
// K_qinit: initial q-partials.  16 blocks (one per K-slice of 32).
// ---------------------------------------------------------------------------
__global__ __launch_bounds__(256) void k_qinit(
    const f16* __restrict__ h0_sw, const f16* __restrict__ WhT_sw,
    float* __restrict__ qpart)
{
    int j = blockIdx.x;
    int tid = threadIdx.x, wave = tid >> 6, lane = tid & 63;
    int col = lane & 15, quad = lane >> 4;
    half8 a[2];
    #pragma unroll
    for (int i = 0; i < 2; ++i)
        a[i] = *(const half8*)(h0_sw + (((wave * 2 + i) * 16 + j) * 64 + lane) * 8);
    for (int nt = 0; nt < 32; ++nt) {
        half8 bfr = *(const half8*)(WhT_sw + ((nt * 16 + j) * 64 + lane) * 8);
        f32x4 q0 = {}, q1 = {};
        q0 = MFMA16(a[0], bfr, q0);
        q1 = MFMA16(a[1], bfr, q1);
        #pragma unroll
        for (int r = 0; r < 4; ++r) {
            qpart[(j * 128 + wave * 32 + quad * 4 + r) * 512 + nt * 16 + col] = q0[r];
            qpart[(j * 128 + wave * 32 + 16 + quad * 4 + r) * 512 + nt * 16 + col] = q1[r];
        }
    }
}

// ---------------------------------------------------------------------------
// K_att (per step): one block (512 thr) per batch row.
// ---------------------------------------------------------------------------
__global__ __launch_bounds__(512) void k_att(
    const f16* __restrict__ proj, const f16* __restrict__ enc_out,
    const float* __restrict__ qpart, const float* __restrict__ attn_b,
    const float* __restrict__ attn_v, const int* __restrict__ trg,
    const f16* __restrict__ dec_emb, f16* __restrict__ x_sw, int t)
{
    int b = blockIdx.x;
    int tid = threadIdx.x, wave = tid >> 6, lane = tid & 63;
    __shared__ float q[512];
    __shared__ float sc[512];
    __shared__ float wred[8], wred2[8];

    if (tid < 512) {
        float s = attn_b[tid];
        #pragma unroll
        for (int jj = 0; jj < 16; ++jj) s += qpart[(jj * 128 + b) * 512 + tid];
        q[tid] = s;
    }
    __syncthreads();

    float qreg[8], vreg[8];
    #pragma unroll
    for (int u = 0; u < 8; ++u) {
        int e = lane * 8 + u;
        qreg[u] = q[e];
        vreg[u] = attn_v[e];
    }
    // scores: wave w handles s = it*8 + w; 4-deep load batching
    for (int ib = 0; ib < 16; ++ib) {
        half8 p[4];
        #pragma unroll
        for (int z = 0; z < 4; ++z) {
            int s = (ib * 4 + z) * 8 + wave;
            p[z] = *(const half8*)(proj + ((size_t)b * 512 + s) * 512 + lane * 8);
        }
        #pragma unroll
        for (int z = 0; z < 4; ++z) {
            int s = (ib * 4 + z) * 8 + wave;
            float part = 0.f;
            #pragma unroll
            for (int u = 0; u < 8; ++u)
                part += vreg[u] * ftanh(qreg[u] + (float)p[z][u]);
            #pragma unroll
            for (int o = 32; o; o >>= 1) part += __shfl_xor(part, o);
            if (lane == 0) sc[s] = part;
        }
    }
    __syncthreads();

    // softmax over 512 (one value per thread)
    float s0 = sc[tid];
    float mv = s0;
    #pragma unroll
    for (int o = 32; o; o >>= 1) mv = fmaxf(mv, __shfl_xor(mv, o));
    if (lane == 0) wred[wave] = mv;
    __syncthreads();
    float M = wred[0];
    #pragma unroll
    for (int w = 1; w < 8; ++w) M = fmaxf(M, wred[w]);
    float e0 = __expf(s0 - M);
    float sm = e0;
    #pragma unroll
    for (int o = 32; o; o >>= 1) sm += __shfl_xor(sm, o);
    if (lane == 0) wred2[wave] = sm;
    __syncthreads();
    float den = wred2[0];
    #pragma unroll
    for (int w = 1; w < 8; ++w) den += wred2[w];
    sc[tid] = e0 * (1.f / den);
    __syncthreads();

    // ctx: thread owns d = tid; 4 independent s-streams, batched loads
    float acc4[4] = {};
    for (int s4 = 0; s4 < 128; ++s4) {
        float w[4]; f16 ev[4];
        #pragma unroll
        for (int j3 = 0; j3 < 4; ++j3) {
            int s = j3 * 128 + s4;
            w[j3] = sc[s];
            ev[j3] = enc_out[((size_t)b * 512 + s) * 512 + tid];
        }
        #pragma unroll
        for (int j3 = 0; j3 < 4; ++j3) acc4[j3] += w[j3] * (float)ev[j3];
    }
    float c = (acc4[0] + acc4[1]) + (acc4[2] + acc4[3]);

    // x = [dec_emb[tok] | ctx] written in fragment order (K=640)
    int tok = trg[b * 128 + t];
    if (tid < 128) x_sw[frag_idx(b, tid, 20)] = dec_emb[tok * 128 + tid];
    x_sw[frag_idx(b, 128 + tid, 20)] = (f16)c;
}

// ---------------------------------------------------------------------------
// K_gates (per step): 16 blocks; block j owns matched n-slices g*512+j*32.
// All operands fragment-ordered; fused q-partial GEMM for next step.
// ---------------------------------------------------------------------------
__global__ __launch_bounds__(256) void k_gates(
    const f16* __restrict__ x_sw, const f16* __restrict__ hprev_sw,
    const f16* __restrict__ wih_sw, const f16* __restrict__ whh_sw,
    const float* __restrict__ dec_b, float* __restrict__ c_ws,
    f16* __restrict__ hnext_sw, f16* __restrict__ hhist_sw,
    const f16* __restrict__ WhT_sw, float* __restrict__ qpart, int t)
{
    int j = blockIdx.x;
    int tid = threadIdx.x, wave = tid >> 6, lane = tid & 63;
    int col = lane & 15, quad = lane >> 4;
    __shared__ f16 hsl[128][40];

    f32x4 acc[2][8] = {};   // [m-tile][jt], jt = g*2+u
    for (int ks = 0; ks < 36; ++ks) {
        half8 a[2];
        #pragma unroll
        for (int i = 0; i < 2; ++i) {
            int mtile = wave * 2 + i;
            a[i] = (ks < 20)
                ? *(const half8*)(x_sw + ((mtile * 20 + ks) * 64 + lane) * 8)
                : *(const half8*)(hprev_sw + ((mtile * 16 + (ks - 20)) * 64 + lane) * 8);
        }
        half8 bv[8];
        #pragma unroll
        for (int jt = 0; jt < 8; ++jt) {
            int g = jt >> 1, u = jt & 1;
            int ntile = g * 32 + j * 2 + u;
            bv[jt] = (ks < 20)
                ? *(const half8*)(wih_sw + ((ntile * 20 + ks) * 64 + lane) * 8)
                : *(const half8*)(whh_sw + ((ntile * 16 + (ks - 20)) * 64 + lane) * 8);
        }
        #pragma unroll
        for (int jt = 0; jt < 8; ++jt) {
            acc[0][jt] = MFMA16(a[0], bv[jt], acc[0][jt]);
            acc[1][jt] = MFMA16(a[1], bv[jt], acc[1][jt]);
        }
    }
    float bias[8];
    #pragma unroll
    for (int jt = 0; jt < 8; ++jt) {
        int g = jt >> 1, u = jt & 1;
        bias[jt] = dec_b[g * 512 + j * 32 + u * 16 + col];
    }
    #pragma unroll
    for (int i = 0; i < 2; ++i) {
        #pragma unroll
        for (int r = 0; r < 4; ++r) {
            int b = wave * 32 + i * 16 + quad * 4 + r;
            #pragma unroll
            for (int u = 0; u < 2; ++u) {
                int hl = u * 16 + col, hcol = j * 32 + hl;
                float gi = acc[i][0 + u][r] + bias[0 + u];
                float gf = acc[i][2 + u][r] + bias[2 + u];
                float gg = acc[i][4 + u][r] + bias[4 + u];
                float go = acc[i][6 + u][r] + bias[6 + u];
                float ig = fsig(gi), fg = fsig(gf), g2 = ftanh(gg), og = fsig(go);
                float cv = fg * c_ws[b * 512 + hcol] + ig * g2;
                c_ws[b * 512 + hcol] = cv;
                float h = og * ftanh(cv);
                f16 h16 = (f16)h;
                int fidx = frag_idx(b, hcol, 16);
                hnext_sw[fidx] = h16;
                hhist_sw[t * 65536 + fidx] = h16;
                hsl[b][hl] = h16;   // same-wave rows only
            }
        }
    }
    // fused q-partials for next step (wave reads its own hsl rows)
    half8 aq[2];
    #pragma unroll
    for (int i = 0; i < 2; ++i)
        aq[i] = *(const half8*)(&hsl[wave * 32 + i * 16 + col][quad * 8]);
    for (int nt = 0; nt < 32; ++nt) {
        half8 bq = *(const half8*)(WhT_sw + ((nt * 16 + j) * 64 + lane) * 8);
        f32x4 q0 = {}, q1 = {};
        q0 = MFMA16(aq[0], bq, q0);
        q1 = MFMA16(aq[1], bq, q1);
        #pragma unroll
        for (int r = 0; r < 4; ++r) {
            qpart[(j * 128 + wave * 32 + quad * 4 + r) * 512 + nt * 16 + col] = q0[r];
            qpart[(j * 128 + wave * 32 + 16 + quad * 4 + r) * 512 + nt * 16 + col] = q1[r];
        }
    }
}

// ---------------------------------------------------------------------------
// K_logits: batched over all 127 steps (once).
// ---------------------------------------------------------------------------
__global__ __launch_bounds__(256) void k_logits(
    const f16* __restrict__ hhist_sw, const f16* __restrict__ outWT_sw,
    const float* __restrict__ out_b, float* __restrict__ out)
{
    int bt = blockIdx.x;   // 0..126
    int tid = threadIdx.x, wave = tid >> 6, lane = tid & 63;
    int col = lane & 15, quad = lane >> 4;
    f32x4 acc[2][8] = {};
    for (int ks = 0; ks < 16; ++ks) {
        half8 a[2];
        #pragma unroll
        for (int i = 0; i < 2; ++i)
            a[i] = *(const half8*)(hhist_sw + bt * 65536 + (((wave * 2 + i) * 16 + ks) * 64 + lane) * 8);
        half8 bv[8];
        #pragma unroll
        for (int jt = 0; jt < 8; ++jt)
            bv[jt] = *(const half8*)(outWT_sw + ((jt * 16 + ks) * 64 + lane) * 8);
        #pragma unroll
        for (int jt = 0; jt < 8; ++jt) {
            acc[0][jt] = MFMA16(a[0], bv[jt], acc[0][jt]);
            acc[1][jt] = MFMA16(a[1], bv[jt], acc[1][jt]);
        }
    }
    #pragma unroll
    for (int jt = 0; jt < 8; ++jt) {
        float bias = out_b[jt * 16 + col];
        #pragma unroll
        for (int i = 0; i < 2; ++i)
            #pragma unroll
            for (int r = 0; r < 4; ++r) {
                int br = wave * 32 + i * 16 + quad * 4 + r;
                out[br * 16384 + (bt + 1) * 128 + jt * 16 + col] = acc[i][jt][r] + bias;
            }
    }
}

// ---------------------------------------------------------------------------
extern "C" void kernel_launch(void* const* d_in, const int* in_sizes, int n_in,
                              void* d_out, int out_size, void* d_ws, size_t ws_size,
                              hipStream_t stream)
{
    (void)in_sizes; (void)n_in; (void)out_size;
    if (ws_size < 164000000) return;  // clean bail if workspace too small

    const int*   src     = (const int*)d_in[0];
    const int*   trg     = (const int*)d_in[1];
    const float* enc_emb = (const float*)d_in[2];
    const float* wihf    = (const float*)d_in[3];
    const float* whhf    = (const float*)d_in[4];
    const float* bf_     = (const float*)d_in[5];
    const float* wihb    = (const float*)d_in[6];
    const float* whhb    = (const float*)d_in[7];
    const float* bb_     = (const float*)d_in[8];
    const float* dec_emb = (const float*)d_in[9];
    const float* dec_wih = (const float*)d_in[10];
    const float* dec_whh = (const float*)d_in[11];
    const float* dec_b   = (const float*)d_in[12];
    const float* attn_W  = (const float*)d_in[13];
    const float* attn_b  = (const float*)d_in[14];
    const float* attn_v  = (const float*)d_in[15];
    const float* out_W   = (const float*)d_in[16];
    const float* out_b   = (const float*)d_in[17];
    float* out = (float*)d_out;

    char* p = (char*)d_ws;
    auto carve = [&](size_t n) { char* r = p; p += ((n + 255) & ~(size_t)255); return r; };
    f16*   enc_out   = (f16*)  carve(67108864);   // 65536 x 512 fp16
    f16*   proj      = (f16*)  carve(67108864);   // 65536 x 512 fp16
    f16*   WhT_sw    = (f16*)  carve(524288);
    f16*   WeT       = (f16*)  carve(524288);
    f16*   outWT_sw  = (f16*)  carve(131072);
    f16*   emb16     = (f16*)  carve(32768);
    f16*   wihf16    = (f16*)  carve(262144);
    f16*   wihb16    = (f16*)  carve(262144);
    f16*   whhf_sw   = (f16*)  carve(524288);
    f16*   whhb_sw   = (f16*)  carve(524288);
    f16*   decemb16  = (f16*)  carve(32768);
    f16*   decwih_sw = (f16*)  carve(2621440);
    f16*   decwhh_sw = (f16*)  carve(2097152);
    float* qpart     = (float*)carve(4194304);
    f16*   hdec0     = (f16*)  carve(131072);     // fragment order (K=512)
    f16*   hdec1     = (f16*)  carve(131072);
    float* c_ws      = (float*)carve(262144);
    f16*   x_sw      = (f16*)  carve(163840);     // fragment order (K=640)
    f16*   hhist_sw  = (f16*)  carve(16646144);   // 127 x (128x512) frag order
    f16*   xg_vocab  = (f16*)  carve(524288);

    k_prep<<<14784, 256, 0, stream>>>(attn_W, out_W, enc_emb, wihf, wihb, whhf, whhb,
                                      dec_emb, dec_wih, dec_whh,
                                      WhT_sw, outWT_sw, whhf_sw, whhb_sw,
                                      decwih_sw, decwhh_sw, WeT, emb16,
                                      wihf16, wihb16, decemb16, out);
    k_vocab<<<16, 256, 0, stream>>>(emb16, wihf16, wihb16, bf_, bb_, xg_vocab);
    k_enc<<<16, 512, 0, stream>>>(src, xg_vocab, whhf_sw, whhb_sw, enc_out, hdec0, c_ws);
    k_proj<<<2048, 256, 0, stream>>>(enc_out, WeT, proj);
    k_qinit<<<16, 256, 0, stream>>>(hdec0, WhT_sw, qpart);
    for (int t = 0; t < 127; ++t) {
        k_att<<<128, 512, 0, stream>>>(proj, enc_out, qpart, attn_b, attn_v,
                                       trg, decemb16, x_sw, t);
        f16* hin  = (t & 1) ? hdec1 : hdec0;
        f16* hout = (t & 1) ? hdec0 : hdec1;
        k_gates<<<16, 256, 0, stream>>>(x_sw, hin, decwih_sw, decwhh_sw, dec_b,
                                        c_ws, hout, hhist_sw, WhT_sw, qpart, t);
    }
    k_logits<<<127, 256, 0, stream>>>(hhist_sw, outWT_sw, out_b, out);
}